// Round 4
// baseline (155.403 us; speedup 1.0000x reference)
//
#include <hip/hip_runtime.h>
#include <hip/hip_bf16.h>

#define B_ 2
#define S_ 2048
#define D_ 1024
#define H_ 16
#define DH_ 64

typedef __attribute__((ext_vector_type(8))) short bf16x8;
typedef __attribute__((ext_vector_type(4))) float f32x4;

// 0.125 (1/sqrt(DH)) * log2(e): Q pre-scale so attention scores are in exp2 domain
#define QSCALE 0.18033688011112042f

__device__ __forceinline__ ushort f2b(float f){
  __hip_bfloat16 h = __float2bfloat16(f);
  return *reinterpret_cast<ushort*>(&h);
}

__device__ __forceinline__ unsigned cvtpk(float lo, float hi){
  unsigned r;
  asm("v_cvt_pk_bf16_f32 %0, %1, %2" : "=v"(r) : "v"(lo), "v"(hi));
  return r;
}

__device__ __forceinline__ void gload16(const ushort* g, ushort* l){
  __builtin_amdgcn_global_load_lds((const __attribute__((address_space(1))) unsigned*)g,
                                   (__attribute__((address_space(3))) unsigned*)l, 16, 0, 0);
}

// ---------------- fused prep: x f32->bf16 convert + 4 weight transposes ----------------
__global__ __launch_bounds__(256) void k_prep(const float* __restrict__ x, ushort* __restrict__ xb,
                                              const float* __restrict__ Wq, const float* __restrict__ Wk,
                                              const float* __restrict__ Wv, const float* __restrict__ Wo,
                                              ushort* __restrict__ WqkvT, ushort* __restrict__ WoT){
  int bid = blockIdx.x, tid = threadIdx.x;
  if (bid < 2048){
    int i = (bid*256 + tid)*8;
    float4 v0 = *(const float4*)(x + i);
    float4 v1 = *(const float4*)(x + i + 4);
    uint4 o;
    o.x = f2b(v0.x) | ((unsigned)f2b(v0.y)<<16);
    o.y = f2b(v0.z) | ((unsigned)f2b(v0.w)<<16);
    o.z = f2b(v1.x) | ((unsigned)f2b(v1.y)<<16);
    o.w = f2b(v1.z) | ((unsigned)f2b(v1.w)<<16);
    *(uint4*)(xb + i) = o;
    return;
  }
  bid -= 2048;
  const int w = bid >> 10, tb = bid & 1023;
  const float* src = (w==0)?Wq:(w==1)?Wk:(w==2)?Wv:Wo;
  ushort* dst = (w==3)?WoT : WqkvT + (size_t)w*(1024*1024);
  __shared__ float tile[32][33];
  const int bx2 = tb & 31, by2 = tb >> 5;
  const int c0 = bx2*32, r0 = by2*32;
  const int tx = tid & 31, ty = tid >> 5;
  #pragma unroll
  for (int i=0;i<4;i++)
    tile[ty + i*8][tx] = src[(size_t)(r0 + ty + i*8)*1024 + c0 + tx];
  __syncthreads();
  #pragma unroll
  for (int i=0;i<4;i++)
    dst[(size_t)(c0 + ty + i*8)*1024 + r0 + tx] = f2b(tile[tx][ty + i*8]);
}

// ---------------- bf16 MFMA GEMM: C[M,N] = A[M,K] * BT[N,K]^T + bias ----------------
// OUT=1: f32 row-major, bias=b0.
// OUT=3: fused QKV routing by 1024-col segment: 0 -> Qb bf16 (QSCALE), 1 -> Kb bf16,
//        2 -> Vt transposed [(b*1024 + dh)][2048]. Biases b0/b1/b2 per segment.
// Double-buffered LDS staging via global_load_lds(16B), source chunk pre-swizzled.
template<int OUT>
__global__ __launch_bounds__(256) void k_gemm_bt(const ushort* __restrict__ A,
                                                 const ushort* __restrict__ BT,
                                                 const float* __restrict__ b0p,
                                                 const float* __restrict__ b1p,
                                                 const float* __restrict__ b2p,
                                                 void* __restrict__ Cp,
                                                 int M, int N, int K){
  __shared__ ushort As[2][128*32];
  __shared__ ushort Bs[2][128*32];
  const int tid = threadIdx.x;
  // XCD-bijective swizzle (grid % 8 == 0)
  int bid = blockIdx.x;
  const int cpx = gridDim.x >> 3;
  bid = (bid & 7)*cpx + (bid >> 3);
  const int nbn = N >> 7;
  const int bm = bid / nbn, bn = bid % nbn;
  const int m0 = bm << 7, n0 = bn << 7;
  const int wave = tid >> 6, lane = tid & 63;
  const int wm = (wave >> 1) << 6, wn = (wave & 1) << 6;
  const int lr = lane & 15, lq = lane >> 4;

  f32x4 acc[4][4] = {};

  // chunk c -> row=c>>2, slot=c&3; source global chunk = slot ^ (row&3); LDS linear.
  const int c0 = tid,       r0 = c0 >> 2, k0 = (c0 & 3) ^ (r0 & 3);
  const int c1 = tid + 256, r1 = c1 >> 2, k1 = (c1 & 3) ^ (r1 & 3);
  const ushort* Ag0 = A  + (size_t)(m0 + r0)*K + k0*8;
  const ushort* Ag1 = A  + (size_t)(m0 + r1)*K + k1*8;
  const ushort* Bg0 = BT + (size_t)(n0 + r0)*K + k0*8;
  const ushort* Bg1 = BT + (size_t)(n0 + r1)*K + k1*8;
  const int lo0 = tid*8, lo1 = tid*8 + 2048;

  #define STAGE(kt, buf) { \
    gload16(Ag0 + (kt), &As[buf][lo0]); \
    gload16(Ag1 + (kt), &As[buf][lo1]); \
    gload16(Bg0 + (kt), &Bs[buf][lo0]); \
    gload16(Bg1 + (kt), &Bs[buf][lo1]); }

  STAGE(0, 0);
  __syncthreads();
  int cur = 0;
  for (int kt = 0; kt < K; kt += 32){
    if (kt + 32 < K) STAGE(kt + 32, cur^1);
    bf16x8 af[4], bfr[4];
    #pragma unroll
    for (int i=0;i<4;i++){
      int ra = wm + i*16 + lr;
      af[i]  = *(bf16x8*)&As[cur][ra*32 + ((lq ^ (ra & 3)) << 3)];
      int rb = wn + i*16 + lr;
      bfr[i] = *(bf16x8*)&Bs[cur][rb*32 + ((lq ^ (rb & 3)) << 3)];
    }
    __builtin_amdgcn_s_setprio(1);
    #pragma unroll
    for (int mi=0;mi<4;mi++)
      #pragma unroll
      for (int ni=0;ni<4;ni++)
        acc[mi][ni] = __builtin_amdgcn_mfma_f32_16x16x32_bf16(af[mi], bfr[ni], acc[mi][ni], 0, 0, 0);
    __builtin_amdgcn_s_setprio(0);
    if (kt + 32 < K){
      __syncthreads();               // drains vmcnt for next tile's loads
      cur ^= 1;
    }
  }
  #undef STAGE

  const int seg = n0 >> 10;
  const float* bp = (OUT==1) ? b0p : (seg==0 ? b0p : (seg==1 ? b1p : b2p));
  #pragma unroll
  for (int mi=0;mi<4;mi++){
    #pragma unroll
    for (int ni=0;ni<4;ni++){
      int col = n0 + wn + ni*16 + lr;
      int cl = col & 1023;
      float bv = bp[(OUT==1) ? col : cl];
      int row0 = m0 + wm + mi*16 + lq*4;
      if (OUT == 1){
        #pragma unroll
        for (int r=0;r<4;r++)
          ((float*)Cp)[(size_t)(row0+r)*N + col] = acc[mi][ni][r] + bv;
      } else { // OUT == 3
        ushort* Qb = (ushort*)Cp;
        if (seg == 0){
          #pragma unroll
          for (int r=0;r<4;r++)
            Qb[(size_t)(row0+r)*1024 + cl] = f2b((acc[mi][ni][r] + bv) * QSCALE);
        } else if (seg == 1){
          ushort* Kb = Qb + (4u<<20);
          #pragma unroll
          for (int r=0;r<4;r++)
            Kb[(size_t)(row0+r)*1024 + cl] = f2b(acc[mi][ni][r] + bv);
        } else {
          ushort* Vt = Qb + (8u<<20);
          int bb = row0 >> 11, srow = row0 & 2047;
          uint2 pk;
          pk.x = cvtpk(acc[mi][ni][0]+bv, acc[mi][ni][1]+bv);
          pk.y = cvtpk(acc[mi][ni][2]+bv, acc[mi][ni][3]+bv);
          *(uint2*)&Vt[((size_t)(bb*1024 + cl))*2048 + srow] = pk;
        }
      }
    }
  }
}

// ---------------- MFMA flash attention ----------------
// 1024 blocks, XCD-decoded: xcd=bid&7 owns bh in {xcd*4..xcd*4+3} (K/V L2-resident),
// qt descending (heavy first). 256 thr = 4 waves; wave wq owns q rows wq*16..+16.
// Swapped QK^T (log2-domain scores), defer-max, row-sum via ones-MFMA,
// double-buffered K/V staging via global_load_lds.
__device__ __forceinline__ bf16x8 lds_frag(const ushort* base, int row, int colbytes){
  return *(const bf16x8*)((const char*)base + row*128 + (colbytes ^ ((row & 7) << 4)));
}

__global__ __launch_bounds__(256) void k_attn_mfma(const ushort* __restrict__ Qb,
                                                   const ushort* __restrict__ Kb,
                                                   const ushort* __restrict__ Vtg,
                                                   ushort* __restrict__ Ob){
  __shared__ ushort Ks[2][64*64];
  __shared__ ushort Vs[2][64*64];
  __shared__ ushort Ps[4][16*64];
  const int bx = blockIdx.x;
  const int xcd = bx & 7, ii = bx >> 3;
  const int bh = xcd*4 + (ii & 3);
  const int qt = 31 - (ii >> 2);
  const int h = bh & 15, b = bh >> 4;
  const int q0 = qt << 6;
  const int tid = threadIdx.x;
  const int wq = tid >> 6, lane = tid & 63;
  const int ql = lane & 15, g = lane >> 4;

  bf16x8 Qf0, Qf1;
  {
    const ushort* qp = Qb + (size_t)(b*S_ + q0 + wq*16 + ql)*1024 + h*64 + g*8;
    Qf0 = *(const bf16x8*)(qp);
    Qf1 = *(const bf16x8*)(qp + 32);
  }
  bf16x8 ones;
  #pragma unroll
  for (int i=0;i<8;i++) ones[i] = (short)0x3F80;

  float mst = -1e30f;
  f32x4 lsum = {};
  f32x4 acc[4] = {};

  // staging: thread owns chunks tid (rows 0..31) and tid+256 (rows 32..63); LDS linear,
  // global source chunk pre-swizzled: gk = slot ^ (row & 7)
  const int r0c = tid >> 3, cc = tid & 7;
  const int r1c = r0c + 32;
  const int gk0 = cc ^ (r0c & 7);
  const int gk1 = cc ^ (r1c & 7);
  const ushort* Kp0 = Kb  + (size_t)(b*S_ + r0c)*1024 + h*64 + gk0*8;
  const ushort* Kp1 = Kb  + (size_t)(b*S_ + r1c)*1024 + h*64 + gk1*8;
  const ushort* Vp0 = Vtg + (size_t)(bh*64 + r0c)*2048 + gk0*8;
  const ushort* Vp1 = Vtg + (size_t)(bh*64 + r1c)*2048 + gk1*8;
  const int lo0 = tid*8, lo1 = tid*8 + 2048;

  #define ASTAGE(t, buf) { \
    const size_t ko = (size_t)(t)*65536; \
    gload16(Kp0 + ko, &Ks[buf][lo0]); \
    gload16(Kp1 + ko, &Ks[buf][lo1]); \
    gload16(Vp0 + (t)*64, &Vs[buf][lo0]); \
    gload16(Vp1 + (t)*64, &Vs[buf][lo1]); }

  char* Pb = (char*)Ps + wq*2048;

  ASTAGE(0, 0);
  __syncthreads();
  int cur = 0;
  for (int kt = 0; ; ++kt){
    if (kt < qt) ASTAGE(kt+1, cur^1);

    // ---- QK^T (swapped): sf[ki] row=key ki*16+g*4+r, col=q=ql ----
    f32x4 sf[4] = {};
    __builtin_amdgcn_s_setprio(1);
    #pragma unroll
    for (int ki=0; ki<4; ++ki){
      bf16x8 kf = lds_frag(Ks[cur], ki*16 + ql, g*16);
      sf[ki] = __builtin_amdgcn_mfma_f32_16x16x32_bf16(kf, Qf0, sf[ki], 0, 0, 0);
    }
    #pragma unroll
    for (int ki=0; ki<4; ++ki){
      bf16x8 kf = lds_frag(Ks[cur], ki*16 + ql, 64 + g*16);
      sf[ki] = __builtin_amdgcn_mfma_f32_16x16x32_bf16(kf, Qf1, sf[ki], 0, 0, 0);
    }
    __builtin_amdgcn_s_setprio(0);

    // ---- online softmax (log2 domain) ----
    float s[16];
    #pragma unroll
    for (int ki=0; ki<4; ++ki)
      #pragma unroll
      for (int r=0; r<4; ++r)
        s[ki*4+r] = sf[ki][r];
    if (kt == qt){
      const int th = wq*16 + ql;
      #pragma unroll
      for (int ki=0; ki<4; ++ki)
        #pragma unroll
        for (int r=0; r<4; ++r)
          if (ki*16 + g*4 + r > th) s[ki*4+r] = -1e30f;
    }
    float t0 = fmaxf(fmaxf(s[0], s[1]), s[2]);
    float t1 = fmaxf(fmaxf(s[3], s[4]), s[5]);
    float t2 = fmaxf(fmaxf(s[6], s[7]), s[8]);
    float t3 = fmaxf(fmaxf(s[9], s[10]), s[11]);
    float t4 = fmaxf(fmaxf(s[12], s[13]), s[14]);
    float mt = fmaxf(fmaxf(fmaxf(t0, t1), fmaxf(t2, t3)), fmaxf(t4, s[15]));
    mt = fmaxf(mt, __shfl_xor(mt, 16, 64));
    mt = fmaxf(mt, __shfl_xor(mt, 32, 64));
    if (__any(mt > mst + 8.f)){
      float mnew = fmaxf(mst, mt);
      float corr = exp2f(mst - mnew);
      mst = mnew;
      #pragma unroll
      for (int r=0; r<4; ++r){
        float cr = __shfl(corr, g*4 + r, 64);
        lsum[r] *= cr;
        #pragma unroll
        for (int ni=0; ni<4; ++ni) acc[ni][r] *= cr;
      }
    }
    #pragma unroll
    for (int i=0; i<16; ++i) s[i] = exp2f(s[i] - mst);

    // ---- P -> wave-private LDS (row=q, keys packed; cvt_pk) ----
    #pragma unroll
    for (int ki=0; ki<4; ++ki){
      uint2 uu;
      uu.x = cvtpk(s[ki*4+0], s[ki*4+1]);
      uu.y = cvtpk(s[ki*4+2], s[ki*4+3]);
      *(uint2*)(Pb + ql*128 + ((ki*32 + g*8) ^ ((ql & 7) << 4))) = uu;
    }

    // ---- PV + row-sum (ones-MFMA) ----
    __builtin_amdgcn_s_setprio(1);
    #pragma unroll
    for (int ks=0; ks<2; ++ks){
      bf16x8 pf = *(const bf16x8*)(Pb + ql*128 + ((ks*64 + g*16) ^ ((ql & 7) << 4)));
      #pragma unroll
      for (int ni=0; ni<4; ++ni){
        bf16x8 vf = lds_frag(Vs[cur], ni*16 + ql, ks*64 + g*16);
        acc[ni] = __builtin_amdgcn_mfma_f32_16x16x32_bf16(pf, vf, acc[ni], 0, 0, 0);
      }
      lsum = __builtin_amdgcn_mfma_f32_16x16x32_bf16(pf, ones, lsum, 0, 0, 0);
    }
    __builtin_amdgcn_s_setprio(0);

    if (kt == qt) break;
    __syncthreads();                  // drains vmcnt for next tile's loads
    cur ^= 1;
  }
  #undef ASTAGE

  ushort* Op = Ob + (size_t)(b*S_ + q0 + wq*16)*1024 + h*64;
  #pragma unroll
  for (int r=0; r<4; ++r){
    float ir = 1.0f / lsum[r];
    #pragma unroll
    for (int ni=0; ni<4; ++ni)
      Op[(size_t)(g*4 + r)*1024 + ni*16 + ql] = f2b(acc[ni][r] * ir);
  }
}

// ---------------- launch ----------------
extern "C" void kernel_launch(void* const* d_in, const int* in_sizes, int n_in,
                              void* d_out, int out_size, void* d_ws, size_t ws_size,
                              hipStream_t stream){
  const float* x  = (const float*)d_in[0];
  const float* Wq = (const float*)d_in[2];
  const float* bq = (const float*)d_in[3];
  const float* Wk = (const float*)d_in[4];
  const float* bk = (const float*)d_in[5];
  const float* Wv = (const float*)d_in[6];
  const float* bv = (const float*)d_in[7];
  const float* Wo = (const float*)d_in[8];
  const float* bo = (const float*)d_in[9];

  char* ws = (char*)d_ws;
  const size_t MB = 1024u*1024u;
  ushort* xb    = (ushort*)(ws + 0);        // 8MB; reused as attended
  ushort* WqkvT = (ushort*)(ws + 8*MB);     // [3072][1024] bf16 = 6MB
  ushort* WoT   = (ushort*)(ws + 14*MB);    // 2MB
  ushort* Qb    = (ushort*)(ws + 16*MB);    // 8MB (Kb = +8MB, Vt = +16MB)
  ushort* Kb    = (ushort*)(ws + 24*MB);
  ushort* Vtg   = (ushort*)(ws + 32*MB);    // [(b*16+h)*64+dh][2048]
  ushort* attb  = xb;

  const int MN = B_*S_;

  k_prep<<<dim3(6144), dim3(256), 0, stream>>>(x, xb, Wq, Wk, Wv, Wo, WqkvT, WoT);

  // fused QKV projection: M=4096, N=3072, K=1024
  k_gemm_bt<3><<<dim3((MN/128)*(3072/128)), dim3(256), 0, stream>>>(xb, WqkvT, bq, bk, bv, Qb, MN, 3072, 1024);

  k_attn_mfma<<<dim3(1024), dim3(256), 0, stream>>>(Qb, Kb, Vtg, attb);

  k_gemm_bt<1><<<dim3((MN/128)*(1024/128)), dim3(256), 0, stream>>>(attb, WoT, bo, bo, bo, (float*)d_out, MN, 1024, 1024);
}

// Round 5
// 142.129 us; speedup vs baseline: 1.0934x; 1.0934x over previous
//
#include <hip/hip_runtime.h>
#include <hip/hip_bf16.h>

#define B_ 2
#define S_ 2048
#define D_ 1024
#define H_ 16
#define DH_ 64

typedef __attribute__((ext_vector_type(8))) short bf16x8;
typedef __attribute__((ext_vector_type(4))) float f32x4;

// 0.125 (1/sqrt(DH)) * log2(e): Q pre-scale so attention scores are in exp2 domain
#define QSCALE 0.18033688011112042f

__device__ __forceinline__ ushort f2b(float f){
  __hip_bfloat16 h = __float2bfloat16(f);
  return *reinterpret_cast<ushort*>(&h);
}

__device__ __forceinline__ unsigned cvtpk(float lo, float hi){
  unsigned r;
  asm("v_cvt_pk_bf16_f32 %0, %1, %2" : "=v"(r) : "v"(lo), "v"(hi));
  return r;
}

__device__ __forceinline__ void gload16(const ushort* g, ushort* l){
  __builtin_amdgcn_global_load_lds((const __attribute__((address_space(1))) unsigned*)g,
                                   (__attribute__((address_space(3))) unsigned*)l, 16, 0, 0);
}

// ---------------- fused prep: x f32->bf16 convert + 4 weight transposes ----------------
__global__ __launch_bounds__(256) void k_prep(const float* __restrict__ x, ushort* __restrict__ xb,
                                              const float* __restrict__ Wq, const float* __restrict__ Wk,
                                              const float* __restrict__ Wv, const float* __restrict__ Wo,
                                              ushort* __restrict__ WqkvT, ushort* __restrict__ WoT){
  int bid = blockIdx.x, tid = threadIdx.x;
  if (bid < 2048){
    int i = (bid*256 + tid)*8;
    float4 v0 = *(const float4*)(x + i);
    float4 v1 = *(const float4*)(x + i + 4);
    uint4 o;
    o.x = f2b(v0.x) | ((unsigned)f2b(v0.y)<<16);
    o.y = f2b(v0.z) | ((unsigned)f2b(v0.w)<<16);
    o.z = f2b(v1.x) | ((unsigned)f2b(v1.y)<<16);
    o.w = f2b(v1.z) | ((unsigned)f2b(v1.w)<<16);
    *(uint4*)(xb + i) = o;
    return;
  }
  bid -= 2048;
  const int w = bid >> 10, tb = bid & 1023;
  const float* src = (w==0)?Wq:(w==1)?Wk:(w==2)?Wv:Wo;
  ushort* dst = (w==3)?WoT : WqkvT + (size_t)w*(1024*1024);
  __shared__ float tile[32][33];
  const int bx2 = tb & 31, by2 = tb >> 5;
  const int c0 = bx2*32, r0 = by2*32;
  const int tx = tid & 31, ty = tid >> 5;
  #pragma unroll
  for (int i=0;i<4;i++)
    tile[ty + i*8][tx] = src[(size_t)(r0 + ty + i*8)*1024 + c0 + tx];
  __syncthreads();
  #pragma unroll
  for (int i=0;i<4;i++)
    dst[(size_t)(c0 + ty + i*8)*1024 + r0 + tx] = f2b(tile[tx][ty + i*8]);
}

// ---------------- bf16 MFMA GEMM: C[M,N] = A[M,K] * BT[N,K]^T + bias ----------------
// Round-3 proven structure: single-buffer, 2 barriers/K-step, gload_lds 16B,
// pre-swizzled global source chunk, 16KB LDS. No XCD swizzle.
// OUT=1: f32 row-major, bias=b0.
// OUT=3: fused QKV routing by 1024-col segment: 0 -> Qb bf16 (QSCALE), 1 -> Kb bf16,
//        2 -> Vt transposed [(b*1024 + dh)][2048]. Biases b0/b1/b2 per segment.
template<int OUT>
__global__ __launch_bounds__(256) void k_gemm_bt(const ushort* __restrict__ A,
                                                 const ushort* __restrict__ BT,
                                                 const float* __restrict__ b0p,
                                                 const float* __restrict__ b1p,
                                                 const float* __restrict__ b2p,
                                                 void* __restrict__ Cp,
                                                 int M, int N, int K){
  __shared__ ushort As[128*32];
  __shared__ ushort Bs[128*32];
  const int tid = threadIdx.x;
  const int nbn = N >> 7;
  const int bm = blockIdx.x / nbn, bn = blockIdx.x % nbn;
  const int m0 = bm << 7, n0 = bn << 7;
  const int wave = tid >> 6, lane = tid & 63;
  const int wm = (wave >> 1) << 6, wn = (wave & 1) << 6;
  const int lr = lane & 15, lq = lane >> 4;

  f32x4 acc[4][4] = {};

  // chunk c -> row=c>>2, slot=c&3; source global chunk = slot ^ (row&3); LDS linear.
  const int c0 = tid,       r0 = c0 >> 2, k0 = (c0 & 3) ^ (r0 & 3);
  const int c1 = tid + 256, r1 = c1 >> 2, k1 = (c1 & 3) ^ (r1 & 3);
  const ushort* Ag0 = A  + (size_t)(m0 + r0)*K + k0*8;
  const ushort* Ag1 = A  + (size_t)(m0 + r1)*K + k1*8;
  const ushort* Bg0 = BT + (size_t)(n0 + r0)*K + k0*8;
  const ushort* Bg1 = BT + (size_t)(n0 + r1)*K + k1*8;
  ushort* La0 = &As[c0*8];  ushort* La1 = &As[c1*8];
  ushort* Lb0 = &Bs[c0*8];  ushort* Lb1 = &Bs[c1*8];

  for (int kt = 0; kt < K; kt += 32){
    __syncthreads();                 // previous iter's LDS reads done
    gload16(Ag0 + kt, La0);
    gload16(Ag1 + kt, La1);
    gload16(Bg0 + kt, Lb0);
    gload16(Bg1 + kt, Lb1);
    __syncthreads();                 // vmcnt(0) drain + barrier
    bf16x8 af[4], bfr[4];
    #pragma unroll
    for (int i=0;i<4;i++){
      int ra = wm + i*16 + lr;
      af[i]  = *(bf16x8*)&As[ra*32 + ((lq ^ (ra & 3)) << 3)];
      int rb = wn + i*16 + lr;
      bfr[i] = *(bf16x8*)&Bs[rb*32 + ((lq ^ (rb & 3)) << 3)];
    }
    __builtin_amdgcn_s_setprio(1);
    #pragma unroll
    for (int mi=0;mi<4;mi++)
      #pragma unroll
      for (int ni=0;ni<4;ni++)
        acc[mi][ni] = __builtin_amdgcn_mfma_f32_16x16x32_bf16(af[mi], bfr[ni], acc[mi][ni], 0, 0, 0);
    __builtin_amdgcn_s_setprio(0);
  }

  const int seg = n0 >> 10;
  const float* bp = (OUT==1) ? b0p : (seg==0 ? b0p : (seg==1 ? b1p : b2p));
  #pragma unroll
  for (int mi=0;mi<4;mi++){
    #pragma unroll
    for (int ni=0;ni<4;ni++){
      int col = n0 + wn + ni*16 + lr;
      int cl = col & 1023;
      float bv = bp[(OUT==1) ? col : cl];
      int row0 = m0 + wm + mi*16 + lq*4;
      if (OUT == 1){
        #pragma unroll
        for (int r=0;r<4;r++)
          ((float*)Cp)[(size_t)(row0+r)*N + col] = acc[mi][ni][r] + bv;
      } else { // OUT == 3
        ushort* Qb = (ushort*)Cp;
        if (seg == 0){
          #pragma unroll
          for (int r=0;r<4;r++)
            Qb[(size_t)(row0+r)*1024 + cl] = f2b((acc[mi][ni][r] + bv) * QSCALE);
        } else if (seg == 1){
          ushort* Kb = Qb + (4u<<20);
          #pragma unroll
          for (int r=0;r<4;r++)
            Kb[(size_t)(row0+r)*1024 + cl] = f2b(acc[mi][ni][r] + bv);
        } else {
          ushort* Vt = Qb + (8u<<20);
          int bb = row0 >> 11, srow = row0 & 2047;
          uint2 pk;
          pk.x = cvtpk(acc[mi][ni][0]+bv, acc[mi][ni][1]+bv);
          pk.y = cvtpk(acc[mi][ni][2]+bv, acc[mi][ni][3]+bv);
          *(uint2*)&Vt[((size_t)(bb*1024 + cl))*2048 + srow] = pk;
        }
      }
    }
  }
}

// ---------------- MFMA flash attention, QBLK=128 ----------------
// 512 blocks = 16 q-blocks (128 rows) x 32 bh; XCD-decoded, qb descending.
// 4 waves; wave wq owns q rows [wq*32, wq*32+32) as 2 groups u=0,1 of 16.
// K/V frags shared across both u groups (halves LDS reads + staging per q-row).
// Swapped QK^T (log2-domain), defer-max, row-sum via ones-MFMA, gload_lds dbuf.
__device__ __forceinline__ bf16x8 lds_frag(const ushort* base, int row, int colbytes){
  return *(const bf16x8*)((const char*)base + row*128 + (colbytes ^ ((row & 7) << 4)));
}

__global__ __launch_bounds__(256) void k_attn_mfma(const ushort* __restrict__ Qb,
                                                   const ushort* __restrict__ Kb,
                                                   const ushort* __restrict__ Vtg,
                                                   ushort* __restrict__ Ob){
  __shared__ ushort Ks[2][64*64];
  __shared__ ushort Vs[2][64*64];
  __shared__ ushort Ps[4][2][16*64];
  const int bx = blockIdx.x;
  const int xcd = bx & 7, ii = bx >> 3;
  const int bh = xcd*4 + (ii & 3);
  const int qb = 15 - (ii >> 2);          // heavy q-blocks dispatch first
  const int h = bh & 15, b = bh >> 4;
  const int q0 = qb << 7;
  const int tid = threadIdx.x;
  const int wq = tid >> 6, lane = tid & 63;
  const int ql = lane & 15, g = lane >> 4;

  bf16x8 Qf[2][2];
  #pragma unroll
  for (int u=0;u<2;u++){
    const ushort* qp = Qb + (size_t)(b*S_ + q0 + wq*32 + u*16 + ql)*1024 + h*64 + g*8;
    Qf[u][0] = *(const bf16x8*)(qp);
    Qf[u][1] = *(const bf16x8*)(qp + 32);
  }
  bf16x8 ones;
  #pragma unroll
  for (int i=0;i<8;i++) ones[i] = (short)0x3F80;

  float mst[2] = {-1e30f, -1e30f};
  f32x4 lsum[2] = {};
  f32x4 acc[2][4] = {};

  // staging: thread owns chunks tid (rows 0..31), tid+256 (rows 32..63); LDS linear,
  // global source chunk pre-swizzled: gk = slot ^ (row & 7)
  const int r0c = tid >> 3, cc = tid & 7;
  const int r1c = r0c + 32;
  const int gk0 = cc ^ (r0c & 7);
  const int gk1 = cc ^ (r1c & 7);
  const ushort* Kp0 = Kb  + (size_t)(b*S_ + r0c)*1024 + h*64 + gk0*8;
  const ushort* Kp1 = Kb  + (size_t)(b*S_ + r1c)*1024 + h*64 + gk1*8;
  const ushort* Vp0 = Vtg + (size_t)(bh*64 + r0c)*2048 + gk0*8;
  const ushort* Vp1 = Vtg + (size_t)(bh*64 + r1c)*2048 + gk1*8;
  const int lo0 = tid*8, lo1 = tid*8 + 2048;

  #define ASTAGE(t, buf) { \
    const size_t ko = (size_t)(t)*65536; \
    gload16(Kp0 + ko, &Ks[buf][lo0]); \
    gload16(Kp1 + ko, &Ks[buf][lo1]); \
    gload16(Vp0 + (t)*64, &Vs[buf][lo0]); \
    gload16(Vp1 + (t)*64, &Vs[buf][lo1]); }

  char* Pb = (char*)Ps + wq*4096;
  const int NT = 2*qb + 1;                // last kv-tile index

  ASTAGE(0, 0);
  __syncthreads();
  int cur = 0;
  for (int kt = 0; ; ++kt){
    if (kt < NT) ASTAGE(kt+1, cur^1);

    // ---- QK^T (swapped): sf[u][ki] row=key ki*16+g*4+r, col=q=ql ----
    f32x4 sf[2][4] = {};
    __builtin_amdgcn_s_setprio(1);
    #pragma unroll
    for (int ks=0; ks<2; ++ks){
      #pragma unroll
      for (int ki=0; ki<4; ++ki){
        bf16x8 kf = lds_frag(Ks[cur], ki*16 + ql, ks*64 + g*16);
        sf[0][ki] = __builtin_amdgcn_mfma_f32_16x16x32_bf16(kf, Qf[0][ks], sf[0][ki], 0, 0, 0);
        sf[1][ki] = __builtin_amdgcn_mfma_f32_16x16x32_bf16(kf, Qf[1][ks], sf[1][ki], 0, 0, 0);
      }
    }
    __builtin_amdgcn_s_setprio(0);

    // ---- online softmax (log2 domain), per q-group u ----
    #pragma unroll
    for (int u=0; u<2; ++u){
      #define SS(i) sf[u][(i)>>2][(i)&3]
      if (kt >= 2*qb){
        const int th = q0 + wq*32 + u*16 + ql - kt*64;  // max visible key-in-tile
        #pragma unroll
        for (int ki=0; ki<4; ++ki)
          #pragma unroll
          for (int r=0; r<4; ++r)
            if (ki*16 + g*4 + r > th) sf[u][ki][r] = -1e30f;
      }
      float t0 = fmaxf(fmaxf(SS(0), SS(1)), SS(2));
      float t1 = fmaxf(fmaxf(SS(3), SS(4)), SS(5));
      float t2 = fmaxf(fmaxf(SS(6), SS(7)), SS(8));
      float t3 = fmaxf(fmaxf(SS(9), SS(10)), SS(11));
      float t4 = fmaxf(fmaxf(SS(12), SS(13)), SS(14));
      float mt = fmaxf(fmaxf(fmaxf(t0, t1), fmaxf(t2, t3)), fmaxf(t4, SS(15)));
      mt = fmaxf(mt, __shfl_xor(mt, 16, 64));
      mt = fmaxf(mt, __shfl_xor(mt, 32, 64));
      if (__any(mt > mst[u] + 8.f)){      // defer-max
        float mnew = fmaxf(mst[u], mt);
        float corr = exp2f(mst[u] - mnew);
        mst[u] = mnew;
        #pragma unroll
        for (int r=0; r<4; ++r){
          float cr = __shfl(corr, g*4 + r, 64);
          lsum[u][r] *= cr;
          #pragma unroll
          for (int ni=0; ni<4; ++ni) acc[u][ni][r] *= cr;
        }
      }
      #pragma unroll
      for (int i=0; i<16; ++i) SS(i) = exp2f(SS(i) - mst[u]);
      // P -> wave-private LDS (row=q, keys packed; cvt_pk)
      #pragma unroll
      for (int ki=0; ki<4; ++ki){
        uint2 uu;
        uu.x = cvtpk(sf[u][ki][0], sf[u][ki][1]);
        uu.y = cvtpk(sf[u][ki][2], sf[u][ki][3]);
        *(uint2*)(Pb + u*2048 + ql*128 + ((ki*32 + g*8) ^ ((ql & 7) << 4))) = uu;
      }
      #undef SS
    }

    // ---- PV + row-sum (ones-MFMA); V frags shared across u ----
    __builtin_amdgcn_s_setprio(1);
    #pragma unroll
    for (int ks=0; ks<2; ++ks){
      const int pofs = ql*128 + ((ks*64 + g*16) ^ ((ql & 7) << 4));
      bf16x8 pf0 = *(const bf16x8*)(Pb + pofs);
      bf16x8 pf1 = *(const bf16x8*)(Pb + 2048 + pofs);
      #pragma unroll
      for (int ni=0; ni<4; ++ni){
        bf16x8 vf = lds_frag(Vs[cur], ni*16 + ql, ks*64 + g*16);
        acc[0][ni] = __builtin_amdgcn_mfma_f32_16x16x32_bf16(pf0, vf, acc[0][ni], 0, 0, 0);
        acc[1][ni] = __builtin_amdgcn_mfma_f32_16x16x32_bf16(pf1, vf, acc[1][ni], 0, 0, 0);
      }
      lsum[0] = __builtin_amdgcn_mfma_f32_16x16x32_bf16(pf0, ones, lsum[0], 0, 0, 0);
      lsum[1] = __builtin_amdgcn_mfma_f32_16x16x32_bf16(pf1, ones, lsum[1], 0, 0, 0);
    }
    __builtin_amdgcn_s_setprio(0);

    if (kt == NT) break;
    __syncthreads();                  // drains vmcnt for next tile's loads
    cur ^= 1;
  }
  #undef ASTAGE

  #pragma unroll
  for (int u=0; u<2; ++u){
    ushort* Op = Ob + (size_t)(b*S_ + q0 + wq*32 + u*16)*1024 + h*64;
    #pragma unroll
    for (int r=0; r<4; ++r){
      float ir = 1.0f / lsum[u][r];
      #pragma unroll
      for (int ni=0; ni<4; ++ni)
        Op[(size_t)(g*4 + r)*1024 + ni*16 + ql] = f2b(acc[u][ni][r] * ir);
    }
  }
}

// ---------------- launch ----------------
extern "C" void kernel_launch(void* const* d_in, const int* in_sizes, int n_in,
                              void* d_out, int out_size, void* d_ws, size_t ws_size,
                              hipStream_t stream){
  const float* x  = (const float*)d_in[0];
  const float* Wq = (const float*)d_in[2];
  const float* bq = (const float*)d_in[3];
  const float* Wk = (const float*)d_in[4];
  const float* bk = (const float*)d_in[5];
  const float* Wv = (const float*)d_in[6];
  const float* bv = (const float*)d_in[7];
  const float* Wo = (const float*)d_in[8];
  const float* bo = (const float*)d_in[9];

  char* ws = (char*)d_ws;
  const size_t MB = 1024u*1024u;
  ushort* xb    = (ushort*)(ws + 0);        // 8MB; reused as attended
  ushort* WqkvT = (ushort*)(ws + 8*MB);     // [3072][1024] bf16 = 6MB
  ushort* WoT   = (ushort*)(ws + 14*MB);    // 2MB
  ushort* Qb    = (ushort*)(ws + 16*MB);    // 8MB (Kb = +8MB, Vt = +16MB)
  ushort* Kb    = (ushort*)(ws + 24*MB);
  ushort* Vtg   = (ushort*)(ws + 32*MB);    // [(b*16+h)*64+dh][2048]
  ushort* attb  = xb;

  const int MN = B_*S_;

  k_prep<<<dim3(6144), dim3(256), 0, stream>>>(x, xb, Wq, Wk, Wv, Wo, WqkvT, WoT);

  // fused QKV projection: M=4096, N=3072, K=1024
  k_gemm_bt<3><<<dim3((MN/128)*(3072/128)), dim3(256), 0, stream>>>(xb, WqkvT, bq, bk, bv, Qb, MN, 3072, 1024);

  k_attn_mfma<<<dim3(512), dim3(256), 0, stream>>>(Qb, Kb, Vtg, attb);

  k_gemm_bt<1><<<dim3((MN/128)*(1024/128)), dim3(256), 0, stream>>>(attb, WoT, bo, bo, bo, (float*)d_out, MN, 1024, 1024);
}

// Round 6
// 117.765 us; speedup vs baseline: 1.3196x; 1.2069x over previous
//
#include <hip/hip_runtime.h>
#include <hip/hip_bf16.h>

#define B_ 2
#define S_ 2048
#define D_ 1024
#define H_ 16
#define DH_ 64

typedef __attribute__((ext_vector_type(8))) short bf16x8;
typedef __attribute__((ext_vector_type(4))) float f32x4;

// 0.125 (1/sqrt(DH)) * log2(e): Q pre-scale so attention scores are in exp2 domain
#define QSCALE 0.18033688011112042f

__device__ __forceinline__ ushort f2b(float f){
  __hip_bfloat16 h = __float2bfloat16(f);
  return *reinterpret_cast<ushort*>(&h);
}

__device__ __forceinline__ unsigned cvtpk(float lo, float hi){
  unsigned r;
  asm("v_cvt_pk_bf16_f32 %0, %1, %2" : "=v"(r) : "v"(lo), "v"(hi));
  return r;
}

__device__ __forceinline__ void gload16(const ushort* g, ushort* l){
  __builtin_amdgcn_global_load_lds((const __attribute__((address_space(1))) unsigned*)g,
                                   (__attribute__((address_space(3))) unsigned*)l, 16, 0, 0);
}

// ---------------- fused prep: x f32->bf16 convert + 4 weight transposes ----------------
__global__ __launch_bounds__(256) void k_prep(const float* __restrict__ x, ushort* __restrict__ xb,
                                              const float* __restrict__ Wq, const float* __restrict__ Wk,
                                              const float* __restrict__ Wv, const float* __restrict__ Wo,
                                              ushort* __restrict__ WqkvT, ushort* __restrict__ WoT){
  int bid = blockIdx.x, tid = threadIdx.x;
  if (bid < 2048){
    int i = (bid*256 + tid)*8;
    float4 v0 = *(const float4*)(x + i);
    float4 v1 = *(const float4*)(x + i + 4);
    uint4 o;
    o.x = f2b(v0.x) | ((unsigned)f2b(v0.y)<<16);
    o.y = f2b(v0.z) | ((unsigned)f2b(v0.w)<<16);
    o.z = f2b(v1.x) | ((unsigned)f2b(v1.y)<<16);
    o.w = f2b(v1.z) | ((unsigned)f2b(v1.w)<<16);
    *(uint4*)(xb + i) = o;
    return;
  }
  bid -= 2048;
  const int w = bid >> 10, tb = bid & 1023;
  const float* src = (w==0)?Wq:(w==1)?Wk:(w==2)?Wv:Wo;
  ushort* dst = (w==3)?WoT : WqkvT + (size_t)w*(1024*1024);
  __shared__ float tile[32][33];
  const int bx2 = tb & 31, by2 = tb >> 5;
  const int c0 = bx2*32, r0 = by2*32;
  const int tx = tid & 31, ty = tid >> 5;
  #pragma unroll
  for (int i=0;i<4;i++)
    tile[ty + i*8][tx] = src[(size_t)(r0 + ty + i*8)*1024 + c0 + tx];
  __syncthreads();
  #pragma unroll
  for (int i=0;i<4;i++)
    dst[(size_t)(c0 + ty + i*8)*1024 + r0 + tx] = f2b(tile[tx][ty + i*8]);
}

// ---------------- bf16 MFMA GEMM: C[M,N] = A[M,K] * BT[N,K]^T + bias ----------------
// BK=64: 32KB LDS, single-buffer, 2 barriers per K-step, 32 MFMA + 8 gload_lds(16B)
// per barrier pair. LDS linear for DMA; global source chunk pre-swizzled (slot^(row&7)).
// OUT=1: f32 row-major, bias=b0.
// OUT=3: fused QKV routing by 1024-col segment: 0 -> Qb bf16 (QSCALE), 1 -> Kb bf16,
//        2 -> Vt transposed [(b*1024 + dh)][2048]. Biases b0/b1/b2 per segment.
template<int OUT>
__global__ __launch_bounds__(256) void k_gemm_bt(const ushort* __restrict__ A,
                                                 const ushort* __restrict__ BT,
                                                 const float* __restrict__ b0p,
                                                 const float* __restrict__ b1p,
                                                 const float* __restrict__ b2p,
                                                 void* __restrict__ Cp,
                                                 int M, int N, int K){
  __shared__ ushort As[128*64];
  __shared__ ushort Bs[128*64];
  const int tid = threadIdx.x;
  const int nbn = N >> 7;
  const int bm = blockIdx.x / nbn, bn = blockIdx.x % nbn;
  const int m0 = bm << 7, n0 = bn << 7;
  const int wave = tid >> 6, lane = tid & 63;
  const int wm = (wave >> 1) << 6, wn = (wave & 1) << 6;
  const int lr = lane & 15, lq = lane >> 4;

  f32x4 acc[4][4] = {};

  // chunk c (of 1024): row=c>>3, slot=c&7; source global chunk gk = slot ^ (row&7).
  const ushort* Ag[4]; const ushort* Bg[4]; int lofs[4];
  #pragma unroll
  for (int j=0;j<4;j++){
    int c = tid + j*256, row = c >> 3, slot = c & 7;
    int gk = slot ^ (row & 7);
    Ag[j] = A  + (size_t)(m0 + row)*K + gk*8;
    Bg[j] = BT + (size_t)(n0 + row)*K + gk*8;
    lofs[j] = c*8;
  }

  for (int kt = 0; kt < K; kt += 64){
    __syncthreads();                 // previous iter's LDS reads done
    #pragma unroll
    for (int j=0;j<4;j++){
      gload16(Ag[j] + kt, &As[lofs[j]]);
      gload16(Bg[j] + kt, &Bs[lofs[j]]);
    }
    __syncthreads();                 // vmcnt(0) drain + barrier
    #pragma unroll
    for (int kk=0;kk<2;kk++){
      bf16x8 af[4], bfr[4];
      #pragma unroll
      for (int i=0;i<4;i++){
        int ra = wm + i*16 + lr;
        af[i]  = *(bf16x8*)&As[ra*64 + (((kk*4+lq) ^ (ra & 7)) << 3)];
        int rb = wn + i*16 + lr;
        bfr[i] = *(bf16x8*)&Bs[rb*64 + (((kk*4+lq) ^ (rb & 7)) << 3)];
      }
      __builtin_amdgcn_s_setprio(1);
      #pragma unroll
      for (int mi=0;mi<4;mi++)
        #pragma unroll
        for (int ni=0;ni<4;ni++)
          acc[mi][ni] = __builtin_amdgcn_mfma_f32_16x16x32_bf16(af[mi], bfr[ni], acc[mi][ni], 0, 0, 0);
      __builtin_amdgcn_s_setprio(0);
    }
  }

  const int seg = n0 >> 10;
  const float* bp = (OUT==1) ? b0p : (seg==0 ? b0p : (seg==1 ? b1p : b2p));
  #pragma unroll
  for (int mi=0;mi<4;mi++){
    #pragma unroll
    for (int ni=0;ni<4;ni++){
      int col = n0 + wn + ni*16 + lr;
      int cl = col & 1023;
      float bv = bp[(OUT==1) ? col : cl];
      int row0 = m0 + wm + mi*16 + lq*4;
      if (OUT == 1){
        #pragma unroll
        for (int r=0;r<4;r++)
          ((float*)Cp)[(size_t)(row0+r)*N + col] = acc[mi][ni][r] + bv;
      } else { // OUT == 3
        ushort* Qb = (ushort*)Cp;
        if (seg == 0){
          #pragma unroll
          for (int r=0;r<4;r++)
            Qb[(size_t)(row0+r)*1024 + cl] = f2b((acc[mi][ni][r] + bv) * QSCALE);
        } else if (seg == 1){
          ushort* Kb = Qb + (4u<<20);
          #pragma unroll
          for (int r=0;r<4;r++)
            Kb[(size_t)(row0+r)*1024 + cl] = f2b(acc[mi][ni][r] + bv);
        } else {
          ushort* Vt = Qb + (8u<<20);
          int bb = row0 >> 11, srow = row0 & 2047;
          uint2 pk;
          pk.x = cvtpk(acc[mi][ni][0]+bv, acc[mi][ni][1]+bv);
          pk.y = cvtpk(acc[mi][ni][2]+bv, acc[mi][ni][3]+bv);
          *(uint2*)&Vt[((size_t)(bb*1024 + cl))*2048 + srow] = pk;
        }
      }
    }
  }
}

// ---------------- MFMA flash attention, QBLK=64, causal split-K ----------------
// 1536 blocks. bid<1024: split blocks for qt 16..31 (heavy-first): half0 = upper
// tiles [16,qt] (diag mask), half1 = lower tiles [0,15]; both write unnormalized
// partials (acc -> accP (=d_out scratch), m/l -> mlP). bid>=1024: normal qt 0..15,
// write attb directly. 4 waves x 16 q-rows; swapped QK^T (log2 domain), defer-max,
// row-sum via ones-MFMA, double-buffered K/V staging via global_load_lds.
__device__ __forceinline__ bf16x8 lds_frag(const ushort* base, int row, int colbytes){
  return *(const bf16x8*)((const char*)base + row*128 + (colbytes ^ ((row & 7) << 4)));
}

__global__ __launch_bounds__(256) void k_attn_mfma(const ushort* __restrict__ Qb,
                                                   const ushort* __restrict__ Kb,
                                                   const ushort* __restrict__ Vtg,
                                                   ushort* __restrict__ Ob,
                                                   float* __restrict__ accP,
                                                   float* __restrict__ mlP){
  __shared__ ushort Ks[2][64*64];
  __shared__ ushort Vs[2][64*64];
  __shared__ ushort Ps[4][16*64];
  const int bid = blockIdx.x;
  int bh, qt, t0, NT, half; bool split;
  if (bid < 1024){
    int s = bid >> 5; bh = bid & 31;
    qt = 31 - (s >> 1); half = s & 1; split = true;
    if (half == 0){ t0 = 16; NT = qt; }       // upper (includes diagonal)
    else          { t0 = 0;  NT = 15; }       // lower (fully visible)
  } else {
    int s = bid - 1024; qt = 15 - (s >> 5); bh = s & 31;
    t0 = 0; NT = qt; half = 0; split = false;
  }
  const bool diag = (!split) || (half == 0);
  const int h = bh & 15, b = bh >> 4;
  const int q0 = qt << 6;
  const int tid = threadIdx.x;
  const int wq = tid >> 6, lane = tid & 63;
  const int ql = lane & 15, g = lane >> 4;

  bf16x8 Qf0, Qf1;
  {
    const ushort* qp = Qb + (size_t)(b*S_ + q0 + wq*16 + ql)*1024 + h*64 + g*8;
    Qf0 = *(const bf16x8*)(qp);
    Qf1 = *(const bf16x8*)(qp + 32);
  }
  bf16x8 ones;
  #pragma unroll
  for (int i=0;i<8;i++) ones[i] = (short)0x3F80;

  float mst = -1e30f;
  f32x4 lsum = {};
  f32x4 acc[4] = {};

  const int r0c = tid >> 3, cc = tid & 7;
  const int r1c = r0c + 32;
  const int gk0 = cc ^ (r0c & 7);
  const int gk1 = cc ^ (r1c & 7);
  const ushort* Kp0 = Kb  + (size_t)(b*S_ + r0c)*1024 + h*64 + gk0*8;
  const ushort* Kp1 = Kb  + (size_t)(b*S_ + r1c)*1024 + h*64 + gk1*8;
  const ushort* Vp0 = Vtg + (size_t)(bh*64 + r0c)*2048 + gk0*8;
  const ushort* Vp1 = Vtg + (size_t)(bh*64 + r1c)*2048 + gk1*8;
  const int lo0 = tid*8, lo1 = tid*8 + 2048;

  #define ASTAGE(t, buf) { \
    const size_t ko = (size_t)(t)*65536; \
    gload16(Kp0 + ko, &Ks[buf][lo0]); \
    gload16(Kp1 + ko, &Ks[buf][lo1]); \
    gload16(Vp0 + (t)*64, &Vs[buf][lo0]); \
    gload16(Vp1 + (t)*64, &Vs[buf][lo1]); }

  char* Pb = (char*)Ps + wq*2048;

  ASTAGE(t0, 0);
  __syncthreads();
  int cur = 0;
  for (int kt = t0; ; ++kt){
    if (kt < NT) ASTAGE(kt+1, cur^1);

    // ---- QK^T (swapped): sf[ki] row=key ki*16+g*4+r, col=q=ql ----
    f32x4 sf[4] = {};
    __builtin_amdgcn_s_setprio(1);
    #pragma unroll
    for (int ki=0; ki<4; ++ki){
      bf16x8 kf = lds_frag(Ks[cur], ki*16 + ql, g*16);
      sf[ki] = __builtin_amdgcn_mfma_f32_16x16x32_bf16(kf, Qf0, sf[ki], 0, 0, 0);
    }
    #pragma unroll
    for (int ki=0; ki<4; ++ki){
      bf16x8 kf = lds_frag(Ks[cur], ki*16 + ql, 64 + g*16);
      sf[ki] = __builtin_amdgcn_mfma_f32_16x16x32_bf16(kf, Qf1, sf[ki], 0, 0, 0);
    }
    __builtin_amdgcn_s_setprio(0);

    // ---- online softmax (log2 domain) ----
    float s[16];
    #pragma unroll
    for (int ki=0; ki<4; ++ki)
      #pragma unroll
      for (int r=0; r<4; ++r)
        s[ki*4+r] = sf[ki][r];
    if (diag && kt == NT){
      const int th = q0 + wq*16 + ql - NT*64;   // max visible key-in-tile
      #pragma unroll
      for (int ki=0; ki<4; ++ki)
        #pragma unroll
        for (int r=0; r<4; ++r)
          if (ki*16 + g*4 + r > th) s[ki*4+r] = -1e30f;
    }
    float t0m = fmaxf(fmaxf(s[0], s[1]), s[2]);
    float t1m = fmaxf(fmaxf(s[3], s[4]), s[5]);
    float t2m = fmaxf(fmaxf(s[6], s[7]), s[8]);
    float t3m = fmaxf(fmaxf(s[9], s[10]), s[11]);
    float t4m = fmaxf(fmaxf(s[12], s[13]), s[14]);
    float mt = fmaxf(fmaxf(fmaxf(t0m, t1m), fmaxf(t2m, t3m)), fmaxf(t4m, s[15]));
    mt = fmaxf(mt, __shfl_xor(mt, 16, 64));
    mt = fmaxf(mt, __shfl_xor(mt, 32, 64));
    if (__any(mt > mst + 8.f)){                 // defer-max
      float mnew = fmaxf(mst, mt);
      float corr = exp2f(mst - mnew);
      mst = mnew;
      #pragma unroll
      for (int r=0; r<4; ++r){
        float cr = __shfl(corr, g*4 + r, 64);
        lsum[r] *= cr;
        #pragma unroll
        for (int ni=0; ni<4; ++ni) acc[ni][r] *= cr;
      }
    }
    #pragma unroll
    for (int i=0; i<16; ++i) s[i] = exp2f(s[i] - mst);

    // ---- P -> wave-private LDS (row=q, keys packed; cvt_pk) ----
    #pragma unroll
    for (int ki=0; ki<4; ++ki){
      uint2 uu;
      uu.x = cvtpk(s[ki*4+0], s[ki*4+1]);
      uu.y = cvtpk(s[ki*4+2], s[ki*4+3]);
      *(uint2*)(Pb + ql*128 + ((ki*32 + g*8) ^ ((ql & 7) << 4))) = uu;
    }

    // ---- PV + row-sum (ones-MFMA) ----
    __builtin_amdgcn_s_setprio(1);
    #pragma unroll
    for (int ks=0; ks<2; ++ks){
      bf16x8 pf = *(const bf16x8*)(Pb + ql*128 + ((ks*64 + g*16) ^ ((ql & 7) << 4)));
      #pragma unroll
      for (int ni=0; ni<4; ++ni){
        bf16x8 vf = lds_frag(Vs[cur], ni*16 + ql, ks*64 + g*16);
        acc[ni] = __builtin_amdgcn_mfma_f32_16x16x32_bf16(pf, vf, acc[ni], 0, 0, 0);
      }
      lsum = __builtin_amdgcn_mfma_f32_16x16x32_bf16(pf, ones, lsum, 0, 0, 0);
    }
    __builtin_amdgcn_s_setprio(0);

    if (kt == NT) break;
    __syncthreads();                  // drains vmcnt for next tile's loads
    cur ^= 1;
  }
  #undef ASTAGE

  if (!split){
    ushort* Op = Ob + (size_t)(b*S_ + q0 + wq*16)*1024 + h*64;
    #pragma unroll
    for (int r=0; r<4; ++r){
      float ir = 1.0f / lsum[r];
      #pragma unroll
      for (int ni=0; ni<4; ++ni)
        Op[(size_t)(g*4 + r)*1024 + ni*16 + ql] = f2b(acc[ni][r] * ir);
    }
  } else {
    const int slot = (qt - 16)*32 + bh;
    const int rbase = (half*512 + slot)*64 + wq*16;
    #pragma unroll
    for (int r=0; r<4; ++r){
      const int tr = rbase + g*4 + r;
      float m_row = __shfl(mst, g*4 + r, 64);
      #pragma unroll
      for (int ni=0; ni<4; ++ni)
        accP[(size_t)tr*64 + ni*16 + ql] = acc[ni][r];
      if (ql == 0)
        *(float2*)(mlP + tr*2) = make_float2(m_row, lsum[r]);
    }
  }
}

// ---------------- combine split-K partials ----------------
// 512 blocks (one per (qt>=16, bh) slot), 256 threads: thread = (row=tid>>2, 16 dims).
__global__ __launch_bounds__(256) void k_combine(const float* __restrict__ accP,
                                                 const float* __restrict__ mlP,
                                                 ushort* __restrict__ Ob){
  const int slot = blockIdx.x;
  const int qt = 16 + (slot >> 5), bh = slot & 31;
  const int b = bh >> 4, h = bh & 15;
  const int row = threadIdx.x >> 2, dq = (threadIdx.x & 3) * 16;
  const int trA = slot*64 + row, trB = (512 + slot)*64 + row;
  float2 mlA = *(const float2*)(mlP + trA*2);
  float2 mlB = *(const float2*)(mlP + trB*2);
  float M = fmaxf(mlA.x, mlB.x);
  float wA = exp2f(mlA.x - M), wB = exp2f(mlB.x - M);
  float inv = 1.0f / (mlA.y*wA + mlB.y*wB);
  wA *= inv; wB *= inv;
  const float* pa = accP + (size_t)trA*64 + dq;
  const float* pb = accP + (size_t)trB*64 + dq;
  ushort* op = Ob + (size_t)(b*S_ + qt*64 + row)*1024 + h*64 + dq;
  uint4 o0, o1;
  unsigned ow[8];
  #pragma unroll
  for (int e=0;e<8;e++){
    float2 va = *(const float2*)(pa + e*2);
    float2 vb = *(const float2*)(pb + e*2);
    ow[e] = cvtpk(va.x*wA + vb.x*wB, va.y*wA + vb.y*wB);
  }
  o0.x=ow[0]; o0.y=ow[1]; o0.z=ow[2]; o0.w=ow[3];
  o1.x=ow[4]; o1.y=ow[5]; o1.z=ow[6]; o1.w=ow[7];
  *(uint4*)(op)     = o0;
  *(uint4*)(op + 8) = o1;
}

// ---------------- launch ----------------
extern "C" void kernel_launch(void* const* d_in, const int* in_sizes, int n_in,
                              void* d_out, int out_size, void* d_ws, size_t ws_size,
                              hipStream_t stream){
  const float* x  = (const float*)d_in[0];
  const float* Wq = (const float*)d_in[2];
  const float* bq = (const float*)d_in[3];
  const float* Wk = (const float*)d_in[4];
  const float* bk = (const float*)d_in[5];
  const float* Wv = (const float*)d_in[6];
  const float* bv = (const float*)d_in[7];
  const float* Wo = (const float*)d_in[8];
  const float* bo = (const float*)d_in[9];

  char* ws = (char*)d_ws;
  const size_t MB = 1024u*1024u;
  ushort* xb    = (ushort*)(ws + 0);        // 8MB; reused as attended
  ushort* WqkvT = (ushort*)(ws + 8*MB);     // [3072][1024] bf16 = 6MB
  ushort* WoT   = (ushort*)(ws + 14*MB);    // 2MB
  ushort* Qb    = (ushort*)(ws + 16*MB);    // 8MB (Kb = +8MB, Vt = +16MB)
  ushort* Kb    = (ushort*)(ws + 24*MB);
  ushort* Vtg   = (ushort*)(ws + 32*MB);    // [(b*16+h)*64+dh][2048]
  float*  mlP   = (float*)(ws + 40*MB);     // 512KB: [2][512][64] float2
  ushort* attb  = xb;
  float*  accP  = (float*)d_out;            // 16MB scratch during attention

  const int MN = B_*S_;

  k_prep<<<dim3(6144), dim3(256), 0, stream>>>(x, xb, Wq, Wk, Wv, Wo, WqkvT, WoT);

  // fused QKV projection: M=4096, N=3072, K=1024
  k_gemm_bt<3><<<dim3((MN/128)*(3072/128)), dim3(256), 0, stream>>>(xb, WqkvT, bq, bk, bv, Qb, MN, 3072, 1024);

  k_attn_mfma<<<dim3(1536), dim3(256), 0, stream>>>(Qb, Kb, Vtg, attb, accP, mlP);
  k_combine<<<dim3(512), dim3(256), 0, stream>>>(accP, mlP, attb);

  k_gemm_bt<1><<<dim3((MN/128)*(1024/128)), dim3(256), 0, stream>>>(attb, WoT, bo, bo, bo, (float*)d_out, MN, 1024, 1024);
}